// Round 12
// baseline (212.842 us; speedup 1.0000x reference)
//
#include <hip/hip_runtime.h>
#include <math.h>

// Match numpy (no FMA contraction) — mask boundary is bit-sensitive.
#pragma clang fp contract(off)

namespace {

constexpr int B = 12, H = 192, W = 640;
constexpr int HW  = H * W;        // 122880
constexpr int BHW = B * HW;       // 1474560
constexpr int NQ  = BHW / 4;      // 368640 quads
constexpr float EPS = 1e-7f;

constexpr int TPB    = 768;       // 12 waves/block
constexpr int GRID   = 480;       // NQ = 480*768 exactly -> one quad/thread, 0 idle
constexpr int NWAVES = TPB / 64;  // 12
// __launch_bounds__(768,6): blocks/CU = 6*4/12 = 2 -> 512 slots >= 480
// co-resident (barrier safe); VGPR cap 512/6 = 85 (vs R10/R11's 64-cap ->
// VGPR_Count=32 + scratch spill = the 116 µs, 9%-VALU mystery).
constexpr int QPB    = NQ / GRID; // 768 quads/block == TPB
constexpr int TR     = 6;
constexpr int TILES  = H / TR;    // 32
constexpr int TRW    = TR * W;    // 3840
constexpr int BPB    = (HW/4) / QPB; // 40 source blocks per batch (12*40=480)
constexpr int SEGCAP = QPB * 4;   // 3072: one block can't emit more per tile
constexpr int GW     = B * TILES; // 384 winner buckets (blocks 0..383)

// ws: redA[GRID*4] @ +0 | redB[GRID*2] @ +8192 | bars[4] u32 @ +12288
//     (cnt0,flag0,cnt1,flag1) | cntA[B*TILES*BPB] @ +16384 (60 KB) |
//     bkt[B*TILES*BPB*SEGCAP] u32 @ +262144 (188.7 MB; ws = 256 MiB)
//
// Single persistent kernel (R10/R11-proven CORRECT: absmax 0 twice).
// R12 changes ONLY the launch geometry: R10/R11's launch_bounds(1024,8)
// capped VGPR at 64, compiler allocated 32 -> cross-phase state spilled to
// scratch -> latency-bound at 455 GB/s / 9% VALU, identical across two
// different barrier implementations (spin mechanics falsified as the cost).
// 768-thread blocks raise the cap to 85 VGPRs with the same 2-blocks/CU
// co-residency guarantee.
// Phases: A (inputs once: mins->redA, bins->bkt/cntA, sx/sy in REGISTERS)
// | bar0 | B (reduce redA; re-load fx/fy L2-hot; check->cva REGISTERS,
// partials->redB) | arrive1 | W (winner resolve, XCD-swizzled, hides in
// wait) | wait1 | C (mask from cva).
// Winner semantics: LWW == max-index-wins via LDS atomicMax(key=(n<<1|seg)+1)
// — bit-exact across R0-R11. min/max exactly associative => regrouped
// reductions bit-identical. All float arithmetic byte-identical to R9-R11.

__device__ __forceinline__ void computeP(const float* __restrict__ Kb,
                                         const float* __restrict__ Po, float* P) {
#pragma unroll
    for (int i = 0; i < 3; ++i)
#pragma unroll
        for (int j = 0; j < 4; ++j) {
            float s = Kb[i*4+0] * Po[0*4+j];
            s = s + Kb[i*4+1] * Po[1*4+j];
            s = s + Kb[i*4+2] * Po[2*4+j];
            s = s + Kb[i*4+3] * Po[3*4+j];
            P[i*4+j] = s;
        }
}

__device__ __forceinline__ void static_flow_P(
    const float* __restrict__ iK, const float* __restrict__ P,
    int x, int y, float d, float& sx, float& sy)
{
    float fx = (float)x, fy = (float)y;
    float cam0 = iK[0]*fx + iK[1]*fy + iK[2];
    float cam1 = iK[4]*fx + iK[5]*fy + iK[6];
    float cam2 = iK[8]*fx + iK[9]*fy + iK[10];
    cam0 = d * cam0; cam1 = d * cam1; cam2 = d * cam2;
    float cp0 = P[0]*cam0 + P[1]*cam1 + P[2]*cam2  + P[3];
    float cp1 = P[4]*cam0 + P[5]*cam1 + P[6]*cam2  + P[7];
    float cp2 = P[8]*cam0 + P[9]*cam1 + P[10]*cam2 + P[11];
    float pz = cp2 + EPS;
    sx = cp0 / pz - fx;
    sy = cp1 / pz - fy;
}

__device__ __forceinline__ float norm01(float v, float mn, float mx) {
    return (2.0f * (v - mn)) / (mx - mn) - 1.0f;
}

__device__ __forceinline__ void blockRed4(float& a0, float& a1, float& a2, float& a3,
                                          float (*sred)[4], float* bc) {
    for (int off = 32; off; off >>= 1) {
        a0 = fminf(a0, __shfl_down(a0, off, 64));
        a1 = fmaxf(a1, __shfl_down(a1, off, 64));
        a2 = fminf(a2, __shfl_down(a2, off, 64));
        a3 = fmaxf(a3, __shfl_down(a3, off, 64));
    }
    int lane = threadIdx.x & 63, wv = threadIdx.x >> 6;
    if (lane == 0) { sred[wv][0]=a0; sred[wv][1]=a1; sred[wv][2]=a2; sred[wv][3]=a3; }
    __syncthreads();
    if (threadIdx.x == 0) {
#pragma unroll
        for (int w = 1; w < NWAVES; ++w) {
            a0 = fminf(a0, sred[w][0]); a1 = fmaxf(a1, sred[w][1]);
            a2 = fminf(a2, sred[w][2]); a3 = fmaxf(a3, sred[w][3]);
        }
        bc[0]=a0; bc[1]=a1; bc[2]=a2; bc[3]=a3;
    }
    __syncthreads();
    a0=bc[0]; a1=bc[1]; a2=bc[2]; a3=bc[3];
}

__device__ __forceinline__ void blockRed2(float& a0, float& a1,
                                          float (*sred)[4], float* bc) {
    for (int off = 32; off; off >>= 1) {
        a0 = fminf(a0, __shfl_down(a0, off, 64));
        a1 = fmaxf(a1, __shfl_down(a1, off, 64));
    }
    int lane = threadIdx.x & 63, wv = threadIdx.x >> 6;
    if (lane == 0) { sred[wv][0]=a0; sred[wv][1]=a1; }
    __syncthreads();
    if (threadIdx.x == 0) {
#pragma unroll
        for (int w = 1; w < NWAVES; ++w) {
            a0 = fminf(a0, sred[w][0]); a1 = fmaxf(a1, sred[w][1]);
        }
        bc[0]=a0; bc[1]=a1;
    }
    __syncthreads();
    a0=bc[0]; a1=bc[1];
}

// Split grid barrier (R11): one atomicAdd per block to arrive; last arriver
// sets flag; waiters LOAD-spin (device-scope acquire load). clock64-bounded
// escape -> failure shows as absmax, never a hang.
__device__ __forceinline__ void barArrive(unsigned* cnt, unsigned* flag) {
    __syncthreads();
    if (threadIdx.x == 0) {
        __threadfence();                        // release
        unsigned old = atomicAdd(cnt, 1u);
        if (old == (unsigned)GRID - 1u) atomicExch(flag, 1u);
    }
}

__device__ __forceinline__ void barWait(unsigned* flag) {
    if (threadIdx.x == 0) {
        long long t0 = clock64();
        while (__hip_atomic_load(flag, __ATOMIC_ACQUIRE,
                                 __HIP_MEMORY_SCOPE_AGENT) == 0u) {
            __builtin_amdgcn_s_sleep(4);
            if (clock64() - t0 > 400000000LL) break;
        }
        __threadfence();                        // acquire
    }
    __syncthreads();
}

__global__ void kInit(unsigned* __restrict__ bars) {
    if (threadIdx.x < 4) bars[threadIdx.x] = 0u;
}

__global__ void __launch_bounds__(TPB, 6)    // 2 blocks/CU, VGPR cap 85
kFused(const float* __restrict__ flow, const float* __restrict__ depth,
       const float* __restrict__ Km, const float* __restrict__ invK,
       const float* __restrict__ pose, const int* __restrict__ seg,
       unsigned* __restrict__ cntA, unsigned* __restrict__ bkt,
       float* __restrict__ redA, float* __restrict__ redB,
       unsigned* __restrict__ bars, float* __restrict__ out)
{
    __shared__ unsigned smem[TRW];           // winner tile (phase W only)
    __shared__ float sred[NWAVES][4];
    __shared__ float bc[4];
    __shared__ unsigned tcnt[TILES];

    const int tid  = threadIdx.x;
    const int bi   = blockIdx.x;
    const int b    = bi / BPB;               // batch (40 blocks per batch)
    const int sblk = bi - b * BPB;           // source block within batch
    const int n0   = sblk * (QPB * 4) + tid * 4;  // batch-local pixel base

    if (tid < TILES) tcnt[tid] = 0u;
    __syncthreads();

    // ================= Phase A: inputs once, mins, bins =================
    float sxa[4], sya[4], cva[4];
    float fmn = INFINITY, fmx = -INFINITY, smn = INFINITY, smx = -INFINITY;
    {
        float P[12];
        computeP(Km + b*16, pose + b*16, P);
        const float* iK = invK + b * 16;
        int y  = n0 / W;                     // quads never cross a row
        int x0 = n0 - y * W;
        float4 fx4 = *(const float4*)(flow + b*2*HW + n0);
        float4 fy4 = *(const float4*)(flow + b*2*HW + HW + n0);
        float4 d4  = *(const float4*)(depth + b*HW + n0);
        int4   s4  = *(const int4*)(seg + b*HW + n0);
        float fxa[4] = {fx4.x, fx4.y, fx4.z, fx4.w};
        float fya[4] = {fy4.x, fy4.y, fy4.z, fy4.w};
        float da[4]  = {d4.x, d4.y, d4.z, d4.w};
        int   sa[4]  = {s4.x, s4.y, s4.z, s4.w};
#pragma unroll
        for (int j = 0; j < 4; ++j) {
            fmn = fminf(fmn, fminf(fxa[j], fya[j]));
            fmx = fmaxf(fmx, fmaxf(fxa[j], fya[j]));
            float sx, sy;
            static_flow_P(iK, P, x0 + j, y, da[j], sx, sy);
            sxa[j] = sx; sya[j] = sy;
            smn = fminf(smn, fminf(sx, sy));
            smx = fmaxf(smx, fmaxf(sx, sy));
            // round-half-even (rintf == jnp.round), clip
            int cxi = (int)rintf((float)(x0 + j) + fxa[j]);
            int cyi = (int)rintf((float)y + fya[j]);
            cxi = min(max(cxi, 0), W - 1);
            cyi = min(max(cyi, 0), H - 1);
            int t   = cyi / TR;
            int pos = (cyi - t * TR) * W + cxi;                  // 12 bits
            unsigned ns = ((unsigned)(n0 + j) << 1) | (sa[j] ? 1u : 0u);
            unsigned e  = (ns << 12) | (unsigned)pos;
            unsigned r  = atomicAdd(&tcnt[t], 1u);
            bkt[((size_t)((b * TILES + t) * BPB + sblk)) * SEGCAP + r] = e;
        }
    }
    blockRed4(fmn, fmx, smn, smx, sred, bc);    // internal syncthreads covers tcnt
    if (tid < TILES) cntA[(b * TILES + tid) * BPB + sblk] = tcnt[tid];
    if (tid == 0) {
        redA[bi*4+0] = fmn; redA[bi*4+1] = fmx;
        redA[bi*4+2] = smn; redA[bi*4+3] = smx;
    }
    barArrive(&bars[0], &bars[1]);
    barWait(&bars[1]);

    // ================= Phase B: check (re-load fx/fy, L2-hot) =================
    float gfmn = INFINITY, gfmx = -INFINITY, gsmn = INFINITY, gsmx = -INFINITY;
    if (tid < GRID) {
        gfmn = redA[tid*4+0]; gfmx = redA[tid*4+1];
        gsmn = redA[tid*4+2]; gsmx = redA[tid*4+3];
    }
    blockRed4(gfmn, gfmx, gsmn, gsmx, sred, bc);

    float cmn = INFINITY, cmx = -INFINITY;
    {
        float4 fx4 = *(const float4*)(flow + b*2*HW + n0);
        float4 fy4 = *(const float4*)(flow + b*2*HW + HW + n0);
        float fxa[4] = {fx4.x, fx4.y, fx4.z, fx4.w};
        float fya[4] = {fy4.x, fy4.y, fy4.z, fy4.w};
#pragma unroll
        for (int j = 0; j < 4; ++j) {
            float dx = norm01(fxa[j], gfmn, gfmx) - norm01(sxa[j], gsmn, gsmx);
            float dy = norm01(fya[j], gfmn, gfmx) - norm01(sya[j], gsmn, gsmx);
            float c = sqrtf(dx*dx + dy*dy);
            cva[j] = c;
            cmn = fminf(cmn, c); cmx = fmaxf(cmx, c);
        }
    }
    blockRed2(cmn, cmx, sred, bc);
    if (tid == 0) { redB[bi*2] = cmn; redB[bi*2+1] = cmx; }
    barArrive(&bars[2], &bars[3]);

    // ===== Phase W: winner resolve (XCD-swizzled) — hides in bar1 wait =====
    if (bi < GW) {
        const int xcd = bi & 7, k = bi >> 3;
        const int wp  = xcd * 48 + k;            // bijective [0,384)
        const int b2  = wp >> 5, t2 = wp & 31;

        for (int i = tid; i < TRW; i += TPB) smem[i] = 0u;
        __syncthreads();

        const int wv = tid >> 6, lane = tid & 63;
        const unsigned* cbase = cntA + (b2 * TILES + t2) * BPB;
        const size_t bktBase = (size_t)(b2 * TILES + t2) * BPB;
        for (int s = wv; s < BPB; s += NWAVES) {
            unsigned c = cbase[s];
            const unsigned* src = bkt + (bktBase + s) * SEGCAP;
            for (unsigned i = lane; i < c; i += 64) {
                unsigned e = src[i];
                atomicMax(&smem[e & 4095u], (e >> 12) + 1u);
            }
        }
        __syncthreads();

        const float* fb = flow + b2 * 2 * HW;
        const int nbase = t2 * TRW;
        for (int q = tid; q < TRW/4; q += TPB) {
            uint4 w4 = *(const uint4*)(smem + q*4);
            unsigned wa[4] = {w4.x, w4.y, w4.z, w4.w};
            float4 bx4, by4, sg4;
            float* bxa = (float*)&bx4;
            float* bya = (float*)&by4;
            float* sga = (float*)&sg4;
#pragma unroll
            for (int j = 0; j < 4; ++j) {
                float bx = 0.0f, by = 0.0f, sg = 0.0f;
                if (wa[j]) {
                    unsigned u = wa[j] - 1u;
                    int nw = (int)(u >> 1);
                    sg = (u & 1u) ? 1.0f : 0.0f;
                    bx = -fb[nw];
                    by = -fb[HW + nw];
                }
                bxa[j] = bx; bya[j] = by; sga[j] = sg;
            }
            int n = nbase + q * 4;
            *(float4*)(out + BHW + b2*2*HW + n)      = bx4;  // bwd_flow x
            *(float4*)(out + BHW + b2*2*HW + HW + n) = by4;  // bwd_flow y
            *(float4*)(out + 3*BHW + b2*HW + n)      = sg4;  // seg_ref
        }
    }
    barWait(&bars[3]);

    // ================= Phase C: mask =================
    float gcmn = INFINITY, gcmx = -INFINITY;
    if (tid < GRID) { gcmn = redB[2*tid]; gcmx = redB[2*tid+1]; }
    blockRed2(gcmn, gcmx, sred, bc);

    {
        int p0 = bi * (QPB * 4) + tid * 4;       // == b*HW + n0
        float4 m4;
        float* ma = (float*)&m4;
#pragma unroll
        for (int j = 0; j < 4; ++j) {
            float cn = (cva[j] - gcmn) / (gcmx - gcmn);
            ma[j] = (cn < 0.98f) ? 1.0f : 0.0f;
        }
        *(float4*)(out + p0) = m4;               // motion_mask
    }
}

} // namespace

extern "C" void kernel_launch(void* const* d_in, const int* in_sizes, int n_in,
                              void* d_out, int out_size, void* d_ws, size_t ws_size,
                              hipStream_t stream) {
    const float* flow  = (const float*)d_in[0];
    const float* depth = (const float*)d_in[1];
    const float* Km    = (const float*)d_in[2];
    const float* invK  = (const float*)d_in[3];
    const float* pose  = (const float*)d_in[4];
    const int*   seg   = (const int*)d_in[5];
    float* out = (float*)d_out;

    float*    redA = (float*)d_ws;                           // 7.5 KB
    float*    redB = (float*)((char*)d_ws + 8192);           // 3.75 KB
    unsigned* bars = (unsigned*)((char*)d_ws + 12288);       // 4 u32
    unsigned* cntA = (unsigned*)((char*)d_ws + 16384);       // 60 KB
    unsigned* bkt  = (unsigned*)((char*)d_ws + 262144);      // 188.7 MB

    kInit <<<1,    64,  0, stream>>>(bars);
    kFused<<<GRID, TPB, 0, stream>>>(flow, depth, Km, invK, pose, seg,
                                     cntA, bkt, redA, redB, bars, out);
}

// Round 13
// 156.802 us; speedup vs baseline: 1.3574x; 1.3574x over previous
//
#include <hip/hip_runtime.h>
#include <math.h>

// Match numpy (no FMA contraction) — mask boundary is bit-sensitive.
#pragma clang fp contract(off)

namespace {

constexpr int B = 12, H = 192, W = 640;
constexpr int HW  = H * W;        // 122880
constexpr int BHW = B * HW;       // 1474560
constexpr int NQ  = BHW / 4;      // 368640 quads
constexpr float EPS = 1e-7f;

constexpr int TPB    = 768;       // 12 waves/block
constexpr int GRID   = 480;       // NQ = 480*768 exactly -> one quad/thread
constexpr int NWAVES = TPB / 64;  // 12
constexpr int QPB    = NQ / GRID; // 768 quads/block == TPB
constexpr int TR     = 6;
constexpr int TILES  = H / TR;    // 32
constexpr int TRW    = TR * W;    // 3840
constexpr int BPB    = (HW/4) / QPB; // 40 source blocks per batch
constexpr int SEGCAP = QPB * 4;   // 3072
constexpr int GW     = B * TILES; // 384 winner buckets (blocks 0..383)

// ws: redA[GRID*4] @ +0 | redB[GRID*2] @ +8192 | bars[4] u32 @ +12288 |
//     cntA[B*TILES*BPB] @ +16384 (60 KB) |
//     bkt[B*TILES*BPB*SEGCAP] u32 @ +262144 (188.7 MB; ws = 256 MiB)
//
// R13 root-cause fix for the fused kernel's 116-138 µs (R10/R11/R12 all
// ~8-9% VALU, ~400-460 GB/s, insensitive to barrier mechanics and geometry;
// cost scaled with BLOCK COUNT): __threadfence on MI355X = per-XCD L2
// writeback (release) / invalidate (acquire), since the 8 XCD L2s are
// non-coherent. Hundreds of blocks x 4+ fences = L2 thrash; every acquire
// made all subsequent reads L2-cold. R13 removes ALL fences: cross-block
// data (bkt, cntA, redA, redB, bars) moves via agent-scope RELAXED atomic
// load/store — sc-flagged, L2-bypassing, visible at the coherent point (L3).
// Barrier = __syncthreads (drains vmcnt -> agent stores at L3) + relaxed
// agent fetch_add + flag + relaxed agent load-spin. Inputs/outputs keep
// normal cached accesses (read-only / runtime-flushed at kernel end).
// clock64 escape -> any visibility failure is a visible absmax, not a hang.
// Phases: A (inputs once: mins->redA, bins->bkt/cntA, sx/sy in REGISTERS)
// | bar0 | B (reduce redA; re-load fx/fy L2-hot; check->cva REGISTERS,
// partials->redB) | arrive1 | W (winner resolve, XCD-swizzled, hides in
// wait) | wait1 | C (mask from cva).
// Winner semantics: LWW == max-index-wins via LDS atomicMax(key=(n<<1|seg)+1)
// — bit-exact across R0-R12. min/max exactly associative => regrouped
// reductions bit-identical. All float arithmetic byte-identical to R9-R12.

__device__ __forceinline__ void stAu(unsigned* p, unsigned v) {
    __hip_atomic_store(p, v, __ATOMIC_RELAXED, __HIP_MEMORY_SCOPE_AGENT);
}
__device__ __forceinline__ unsigned ldAu(const unsigned* p) {
    return __hip_atomic_load(p, __ATOMIC_RELAXED, __HIP_MEMORY_SCOPE_AGENT);
}
__device__ __forceinline__ void stAf(float* p, float v) {
    __hip_atomic_store(p, v, __ATOMIC_RELAXED, __HIP_MEMORY_SCOPE_AGENT);
}
__device__ __forceinline__ float ldAf(const float* p) {
    return __hip_atomic_load(p, __ATOMIC_RELAXED, __HIP_MEMORY_SCOPE_AGENT);
}

__device__ __forceinline__ void computeP(const float* __restrict__ Kb,
                                         const float* __restrict__ Po, float* P) {
#pragma unroll
    for (int i = 0; i < 3; ++i)
#pragma unroll
        for (int j = 0; j < 4; ++j) {
            float s = Kb[i*4+0] * Po[0*4+j];
            s = s + Kb[i*4+1] * Po[1*4+j];
            s = s + Kb[i*4+2] * Po[2*4+j];
            s = s + Kb[i*4+3] * Po[3*4+j];
            P[i*4+j] = s;
        }
}

__device__ __forceinline__ void static_flow_P(
    const float* __restrict__ iK, const float* __restrict__ P,
    int x, int y, float d, float& sx, float& sy)
{
    float fx = (float)x, fy = (float)y;
    float cam0 = iK[0]*fx + iK[1]*fy + iK[2];
    float cam1 = iK[4]*fx + iK[5]*fy + iK[6];
    float cam2 = iK[8]*fx + iK[9]*fy + iK[10];
    cam0 = d * cam0; cam1 = d * cam1; cam2 = d * cam2;
    float cp0 = P[0]*cam0 + P[1]*cam1 + P[2]*cam2  + P[3];
    float cp1 = P[4]*cam0 + P[5]*cam1 + P[6]*cam2  + P[7];
    float cp2 = P[8]*cam0 + P[9]*cam1 + P[10]*cam2 + P[11];
    float pz = cp2 + EPS;
    sx = cp0 / pz - fx;
    sy = cp1 / pz - fy;
}

__device__ __forceinline__ float norm01(float v, float mn, float mx) {
    return (2.0f * (v - mn)) / (mx - mn) - 1.0f;
}

__device__ __forceinline__ void blockRed4(float& a0, float& a1, float& a2, float& a3,
                                          float (*sred)[4], float* bc) {
    for (int off = 32; off; off >>= 1) {
        a0 = fminf(a0, __shfl_down(a0, off, 64));
        a1 = fmaxf(a1, __shfl_down(a1, off, 64));
        a2 = fminf(a2, __shfl_down(a2, off, 64));
        a3 = fmaxf(a3, __shfl_down(a3, off, 64));
    }
    int lane = threadIdx.x & 63, wv = threadIdx.x >> 6;
    if (lane == 0) { sred[wv][0]=a0; sred[wv][1]=a1; sred[wv][2]=a2; sred[wv][3]=a3; }
    __syncthreads();
    if (threadIdx.x == 0) {
#pragma unroll
        for (int w = 1; w < NWAVES; ++w) {
            a0 = fminf(a0, sred[w][0]); a1 = fmaxf(a1, sred[w][1]);
            a2 = fminf(a2, sred[w][2]); a3 = fmaxf(a3, sred[w][3]);
        }
        bc[0]=a0; bc[1]=a1; bc[2]=a2; bc[3]=a3;
    }
    __syncthreads();
    a0=bc[0]; a1=bc[1]; a2=bc[2]; a3=bc[3];
}

__device__ __forceinline__ void blockRed2(float& a0, float& a1,
                                          float (*sred)[4], float* bc) {
    for (int off = 32; off; off >>= 1) {
        a0 = fminf(a0, __shfl_down(a0, off, 64));
        a1 = fmaxf(a1, __shfl_down(a1, off, 64));
    }
    int lane = threadIdx.x & 63, wv = threadIdx.x >> 6;
    if (lane == 0) { sred[wv][0]=a0; sred[wv][1]=a1; }
    __syncthreads();
    if (threadIdx.x == 0) {
#pragma unroll
        for (int w = 1; w < NWAVES; ++w) {
            a0 = fminf(a0, sred[w][0]); a1 = fmaxf(a1, sred[w][1]);
        }
        bc[0]=a0; bc[1]=a1;
    }
    __syncthreads();
    a0=bc[0]; a1=bc[1];
}

// Fence-free grid barrier. __syncthreads drains vmcnt (compiler emits
// s_waitcnt vmcnt(0) before s_barrier) -> all agent-scope stores are at the
// coherent point before arrive. No __threadfence anywhere.
__device__ __forceinline__ void barArrive(unsigned* cnt, unsigned* flag) {
    __syncthreads();
    if (threadIdx.x == 0) {
        unsigned old = __hip_atomic_fetch_add(cnt, 1u, __ATOMIC_RELAXED,
                                              __HIP_MEMORY_SCOPE_AGENT);
        if (old == (unsigned)GRID - 1u) stAu(flag, 1u);
    }
}

__device__ __forceinline__ void barWait(unsigned* flag) {
    if (threadIdx.x == 0) {
        long long t0 = clock64();
        while (ldAu(flag) == 0u) {
            __builtin_amdgcn_s_sleep(4);
            if (clock64() - t0 > 400000000LL) break;   // visible-failure escape
        }
    }
    __syncthreads();
}

__global__ void kInit(unsigned* __restrict__ bars) {
    if (threadIdx.x < 4) stAu(&bars[threadIdx.x], 0u);
}

__global__ void __launch_bounds__(TPB, 6)    // 2 blocks/CU co-resident
kFused(const float* __restrict__ flow, const float* __restrict__ depth,
       const float* __restrict__ Km, const float* __restrict__ invK,
       const float* __restrict__ pose, const int* __restrict__ seg,
       unsigned* __restrict__ cntA, unsigned* __restrict__ bkt,
       float* __restrict__ redA, float* __restrict__ redB,
       unsigned* __restrict__ bars, float* __restrict__ out)
{
    __shared__ unsigned smem[TRW];           // winner tile (phase W only)
    __shared__ float sred[NWAVES][4];
    __shared__ float bc[4];
    __shared__ unsigned tcnt[TILES];

    const int tid  = threadIdx.x;
    const int bi   = blockIdx.x;
    const int b    = bi / BPB;               // batch (40 blocks per batch)
    const int sblk = bi - b * BPB;           // source block within batch
    const int n0   = sblk * (QPB * 4) + tid * 4;  // batch-local pixel base

    if (tid < TILES) tcnt[tid] = 0u;
    __syncthreads();

    // ================= Phase A: inputs once, mins, bins =================
    float sxa[4], sya[4], cva[4];
    float fmn = INFINITY, fmx = -INFINITY, smn = INFINITY, smx = -INFINITY;
    {
        float P[12];
        computeP(Km + b*16, pose + b*16, P);
        const float* iK = invK + b * 16;
        int y  = n0 / W;                     // quads never cross a row
        int x0 = n0 - y * W;
        float4 fx4 = *(const float4*)(flow + b*2*HW + n0);
        float4 fy4 = *(const float4*)(flow + b*2*HW + HW + n0);
        float4 d4  = *(const float4*)(depth + b*HW + n0);
        int4   s4  = *(const int4*)(seg + b*HW + n0);
        float fxa[4] = {fx4.x, fx4.y, fx4.z, fx4.w};
        float fya[4] = {fy4.x, fy4.y, fy4.z, fy4.w};
        float da[4]  = {d4.x, d4.y, d4.z, d4.w};
        int   sa[4]  = {s4.x, s4.y, s4.z, s4.w};
#pragma unroll
        for (int j = 0; j < 4; ++j) {
            fmn = fminf(fmn, fminf(fxa[j], fya[j]));
            fmx = fmaxf(fmx, fmaxf(fxa[j], fya[j]));
            float sx, sy;
            static_flow_P(iK, P, x0 + j, y, da[j], sx, sy);
            sxa[j] = sx; sya[j] = sy;
            smn = fminf(smn, fminf(sx, sy));
            smx = fmaxf(smx, fmaxf(sx, sy));
            // round-half-even (rintf == jnp.round), clip
            int cxi = (int)rintf((float)(x0 + j) + fxa[j]);
            int cyi = (int)rintf((float)y + fya[j]);
            cxi = min(max(cxi, 0), W - 1);
            cyi = min(max(cyi, 0), H - 1);
            int t   = cyi / TR;
            int pos = (cyi - t * TR) * W + cxi;                  // 12 bits
            unsigned ns = ((unsigned)(n0 + j) << 1) | (sa[j] ? 1u : 0u);
            unsigned e  = (ns << 12) | (unsigned)pos;
            unsigned r  = atomicAdd(&tcnt[t], 1u);
            stAu(&bkt[((size_t)((b * TILES + t) * BPB + sblk)) * SEGCAP + r], e);
        }
    }
    blockRed4(fmn, fmx, smn, smx, sred, bc);    // internal syncthreads covers tcnt
    if (tid < TILES) stAu(&cntA[(b * TILES + tid) * BPB + sblk], tcnt[tid]);
    if (tid == 0) {
        stAf(&redA[bi*4+0], fmn); stAf(&redA[bi*4+1], fmx);
        stAf(&redA[bi*4+2], smn); stAf(&redA[bi*4+3], smx);
    }
    barArrive(&bars[0], &bars[1]);
    barWait(&bars[1]);

    // ================= Phase B: check (re-load fx/fy, L2-hot) =================
    float gfmn = INFINITY, gfmx = -INFINITY, gsmn = INFINITY, gsmx = -INFINITY;
    if (tid < GRID) {
        gfmn = ldAf(&redA[tid*4+0]); gfmx = ldAf(&redA[tid*4+1]);
        gsmn = ldAf(&redA[tid*4+2]); gsmx = ldAf(&redA[tid*4+3]);
    }
    blockRed4(gfmn, gfmx, gsmn, gsmx, sred, bc);

    float cmn = INFINITY, cmx = -INFINITY;
    {
        float4 fx4 = *(const float4*)(flow + b*2*HW + n0);
        float4 fy4 = *(const float4*)(flow + b*2*HW + HW + n0);
        float fxa[4] = {fx4.x, fx4.y, fx4.z, fx4.w};
        float fya[4] = {fy4.x, fy4.y, fy4.z, fy4.w};
#pragma unroll
        for (int j = 0; j < 4; ++j) {
            float dx = norm01(fxa[j], gfmn, gfmx) - norm01(sxa[j], gsmn, gsmx);
            float dy = norm01(fya[j], gfmn, gfmx) - norm01(sya[j], gsmn, gsmx);
            float c = sqrtf(dx*dx + dy*dy);
            cva[j] = c;
            cmn = fminf(cmn, c); cmx = fmaxf(cmx, c);
        }
    }
    blockRed2(cmn, cmx, sred, bc);
    if (tid == 0) { stAf(&redB[bi*2], cmn); stAf(&redB[bi*2+1], cmx); }
    barArrive(&bars[2], &bars[3]);

    // ===== Phase W: winner resolve (XCD-swizzled) — hides in bar1 wait =====
    if (bi < GW) {
        const int xcd = bi & 7, k = bi >> 3;
        const int wp  = xcd * 48 + k;            // bijective [0,384)
        const int b2  = wp >> 5, t2 = wp & 31;

        for (int i = tid; i < TRW; i += TPB) smem[i] = 0u;
        __syncthreads();

        const int wv = tid >> 6, lane = tid & 63;
        const unsigned* cbase = cntA + (b2 * TILES + t2) * BPB;
        const size_t bktBase = (size_t)(b2 * TILES + t2) * BPB;
        for (int s = wv; s < BPB; s += NWAVES) {
            unsigned c = ldAu(&cbase[s]);
            const unsigned* src = bkt + (bktBase + s) * SEGCAP;
            for (unsigned i = lane; i < c; i += 64) {
                unsigned e = ldAu(&src[i]);
                atomicMax(&smem[e & 4095u], (e >> 12) + 1u);
            }
        }
        __syncthreads();

        const float* fb = flow + b2 * 2 * HW;
        const int nbase = t2 * TRW;
        for (int q = tid; q < TRW/4; q += TPB) {
            uint4 w4 = *(const uint4*)(smem + q*4);
            unsigned wa[4] = {w4.x, w4.y, w4.z, w4.w};
            float4 bx4, by4, sg4;
            float* bxa = (float*)&bx4;
            float* bya = (float*)&by4;
            float* sga = (float*)&sg4;
#pragma unroll
            for (int j = 0; j < 4; ++j) {
                float bx = 0.0f, by = 0.0f, sg = 0.0f;
                if (wa[j]) {
                    unsigned u = wa[j] - 1u;
                    int nw = (int)(u >> 1);
                    sg = (u & 1u) ? 1.0f : 0.0f;
                    bx = -fb[nw];
                    by = -fb[HW + nw];
                }
                bxa[j] = bx; bya[j] = by; sga[j] = sg;
            }
            int n = nbase + q * 4;
            *(float4*)(out + BHW + b2*2*HW + n)      = bx4;  // bwd_flow x
            *(float4*)(out + BHW + b2*2*HW + HW + n) = by4;  // bwd_flow y
            *(float4*)(out + 3*BHW + b2*HW + n)      = sg4;  // seg_ref
        }
    }
    barWait(&bars[3]);

    // ================= Phase C: mask =================
    float gcmn = INFINITY, gcmx = -INFINITY;
    if (tid < GRID) { gcmn = ldAf(&redB[2*tid]); gcmx = ldAf(&redB[2*tid+1]); }
    blockRed2(gcmn, gcmx, sred, bc);

    {
        int p0 = bi * (QPB * 4) + tid * 4;       // == b*HW + n0
        float4 m4;
        float* ma = (float*)&m4;
#pragma unroll
        for (int j = 0; j < 4; ++j) {
            float cn = (cva[j] - gcmn) / (gcmx - gcmn);
            ma[j] = (cn < 0.98f) ? 1.0f : 0.0f;
        }
        *(float4*)(out + p0) = m4;               // motion_mask
    }
}

} // namespace

extern "C" void kernel_launch(void* const* d_in, const int* in_sizes, int n_in,
                              void* d_out, int out_size, void* d_ws, size_t ws_size,
                              hipStream_t stream) {
    const float* flow  = (const float*)d_in[0];
    const float* depth = (const float*)d_in[1];
    const float* Km    = (const float*)d_in[2];
    const float* invK  = (const float*)d_in[3];
    const float* pose  = (const float*)d_in[4];
    const int*   seg   = (const int*)d_in[5];
    float* out = (float*)d_out;

    float*    redA = (float*)d_ws;                           // 7.5 KB
    float*    redB = (float*)((char*)d_ws + 8192);           // 3.75 KB
    unsigned* bars = (unsigned*)((char*)d_ws + 12288);       // 4 u32
    unsigned* cntA = (unsigned*)((char*)d_ws + 16384);       // 60 KB
    unsigned* bkt  = (unsigned*)((char*)d_ws + 262144);      // 188.7 MB

    kInit <<<1,    64,  0, stream>>>(bars);
    kFused<<<GRID, TPB, 0, stream>>>(flow, depth, Km, invK, pose, seg,
                                     cntA, bkt, redA, redB, bars, out);
}

// Round 15
// 118.558 us; speedup vs baseline: 1.7952x; 1.3226x over previous
//
#include <hip/hip_runtime.h>
#include <math.h>

// Match numpy (no FMA contraction) — mask boundary is bit-sensitive.
#pragma clang fp contract(off)

namespace {

constexpr int B = 12, H = 192, W = 640;
constexpr int HW  = H * W;        // 122880
constexpr int BHW = B * HW;       // 1474560
constexpr int NQ  = BHW / 4;      // 368640 float4 groups
constexpr float EPS = 1e-7f;

// Native clang vector for __builtin_nontemporal_store (HIP float4 is a class
// type the builtin rejects; this alias is layout-identical, 16B).
typedef float vfloat4 __attribute__((ext_vector_type(4)));

// kA / kM: 256-thread blocks, exactly one quad per thread, one generation.
constexpr int TA  = 256;
constexpr int GA  = NQ / TA;      // 1440 blocks
constexpr int BPB = (HW / 4) / TA; // 120 kA-blocks per batch (blocks never cross batch)
constexpr int EPB = TA * 4;       // 1024 entries staged per kA block

constexpr int TR    = 6;          // fine winner-tile rows (spread DS-pipe load)
constexpr int TILES = H / TR;     // 32 tiles/batch
constexpr int TRW   = TR * W;     // 3840 targets/tile (u32 LDS = 15360 B)
constexpr int NBK   = B * TILES;  // 384 buckets == winner blocks
constexpr int GW    = NBK;
constexpr int GC    = 360;        // check blocks: 360*1024*4 == NQ exactly
constexpr int CGRID = GW + GC;    // 744
constexpr int TPB   = 1024;
constexpr int SEGCAP = 1024;      // = sources per kA block -> overflow impossible

// ws layout: redA[GA*4] f32 @ +0 | redB[GC*2] f32 @ +24576 |
//            cntA[B*TILES*BPB] u32 @ +32768 (184 KB, layout [b][t][blk]) |
//            bkt[NBK*BPB*SEGCAP] u32 @ +262144 (188.7 MB; ws = 256 MiB)
// R15 = R14 with the nontemporal-store type fixed (compile error only; the
// builtin needs a native ext_vector pointer, not HIP_vector_type).
// Base: R9 (proven 120.4 µs, absmax 0) + (a) GC=360 exact one-quad-per-thread
// check pass, (b) nontemporal stores for never-re-read outputs (bwd_flow,
// seg_ref, mask) to keep flow/depth/stash L2-resident. Fusion arc (R8-R13)
// abandoned: 3 dispatches sum ~47 µs vs best fused 83 µs.
// Winner semantics: LWW in linear index order == max-index-wins (proven
// bit-exact across R0-R13). kA stages + bucket-sorts entries in LDS, writes
// CONTIGUOUS tile-runs into block-private segments: entry=((n<<1|seg)<<12)|pos.
// Winner block (b,t) scans its 120 count-bounded segments, resolves via LDS
// atomicMax(key=(n<<1|seg)+1, monotone in n => identical winner).
// check[] scratch lives in out[0..BHW) between kBW and kM (proven pattern).
// XCD swizzle (R5/R7-proven): winner blocks remapped xcd=bi&7, wp=xcd*48+
// (bi>>3) so a batch's tile-blocks share an XCD L2 (FETCH 102->21.9 MB).

// P = (K @ pose)[:3,:] — arithmetic identical to reference einsum
// (left-assoc, contract off).
__device__ __forceinline__ void computeP(const float* __restrict__ Kb,
                                         const float* __restrict__ Po, float* P) {
#pragma unroll
    for (int i = 0; i < 3; ++i)
#pragma unroll
        for (int j = 0; j < 4; ++j) {
            float s = Kb[i*4+0] * Po[0*4+j];
            s = s + Kb[i*4+1] * Po[1*4+j];
            s = s + Kb[i*4+2] * Po[2*4+j];
            s = s + Kb[i*4+3] * Po[3*4+j];
            P[i*4+j] = s;
        }
}

__device__ __forceinline__ void static_flow_P(
    const float* __restrict__ iK, const float* __restrict__ P,
    int x, int y, float d, float& sx, float& sy)
{
    float fx = (float)x, fy = (float)y;
    float cam0 = iK[0]*fx + iK[1]*fy + iK[2];
    float cam1 = iK[4]*fx + iK[5]*fy + iK[6];
    float cam2 = iK[8]*fx + iK[9]*fy + iK[10];
    cam0 = d * cam0; cam1 = d * cam1; cam2 = d * cam2;
    float cp0 = P[0]*cam0 + P[1]*cam1 + P[2]*cam2  + P[3];
    float cp1 = P[4]*cam0 + P[5]*cam1 + P[6]*cam2  + P[7];
    float cp2 = P[8]*cam0 + P[9]*cam1 + P[10]*cam2 + P[11];
    float pz = cp2 + EPS;
    sx = cp0 / pz - fx;
    sy = cp1 / pz - fy;
}

__device__ __forceinline__ float norm01(float v, float mn, float mx) {
    return (2.0f * (v - mn)) / (mx - mn) - 1.0f;
}

// Block-wide min/max reduce + broadcast, parameterized on wave count.
template<int NW>
__device__ __forceinline__ void blockRed4T(float& a0, float& a1, float& a2, float& a3,
                                           float (*sred)[4], float* bc) {
    for (int off = 32; off; off >>= 1) {
        a0 = fminf(a0, __shfl_down(a0, off, 64));
        a1 = fmaxf(a1, __shfl_down(a1, off, 64));
        a2 = fminf(a2, __shfl_down(a2, off, 64));
        a3 = fmaxf(a3, __shfl_down(a3, off, 64));
    }
    int lane = threadIdx.x & 63, wv = threadIdx.x >> 6;
    if (lane == 0) { sred[wv][0]=a0; sred[wv][1]=a1; sred[wv][2]=a2; sred[wv][3]=a3; }
    __syncthreads();
    if (threadIdx.x == 0) {
#pragma unroll
        for (int w = 1; w < NW; ++w) {
            a0 = fminf(a0, sred[w][0]); a1 = fmaxf(a1, sred[w][1]);
            a2 = fminf(a2, sred[w][2]); a3 = fmaxf(a3, sred[w][3]);
        }
        bc[0]=a0; bc[1]=a1; bc[2]=a2; bc[3]=a3;
    }
    __syncthreads();
    a0=bc[0]; a1=bc[1]; a2=bc[2]; a3=bc[3];
}

template<int NW>
__device__ __forceinline__ void blockRed2T(float& a0, float& a1,
                                           float (*sred)[4], float* bc) {
    for (int off = 32; off; off >>= 1) {
        a0 = fminf(a0, __shfl_down(a0, off, 64));
        a1 = fmaxf(a1, __shfl_down(a1, off, 64));
    }
    int lane = threadIdx.x & 63, wv = threadIdx.x >> 6;
    if (lane == 0) { sred[wv][0]=a0; sred[wv][1]=a1; }
    __syncthreads();
    if (threadIdx.x == 0) {
#pragma unroll
        for (int w = 1; w < NW; ++w) {
            a0 = fminf(a0, sred[w][0]); a1 = fmaxf(a1, sred[w][1]);
        }
        bc[0]=a0; bc[1]=a1;
    }
    __syncthreads();
    a0=bc[0]; a1=bc[1];
}

// Dispatch 1: one quad/thread — flow min/max + static-flow min/max partials
// into redA; bin each source into LDS, bucket-sort by tile, write coalesced
// tile-runs into block-private bucket segments. No global atomics.
__global__ void __launch_bounds__(TA)
kA(const float* __restrict__ flow, const float* __restrict__ depth,
   const float* __restrict__ Km, const float* __restrict__ invK,
   const float* __restrict__ pose, const int* __restrict__ seg,
   unsigned* __restrict__ cntA, unsigned* __restrict__ bkt,
   float* __restrict__ redA)
{
    __shared__ float sred[4][4];
    __shared__ float bc[4];
    __shared__ unsigned ecnt[TILES];
    __shared__ unsigned ebase[TILES];
    __shared__ unsigned sbuf[EPB];            // 4 KB staging

    if (threadIdx.x < TILES) ecnt[threadIdx.x] = 0u;
    __syncthreads();

    int p0 = blockIdx.x * EPB + threadIdx.x * 4;        // < BHW
    int b  = blockIdx.x / BPB;
    int blkInB = blockIdx.x - b * BPB;
    float P[12];
    computeP(Km + b*16, pose + b*16, P);
    const float* iK = invK + b * 16;
    int n0 = p0 - b * HW;
    int y  = n0 / W;                 // quads never cross a row (W%4==0)
    int x0 = n0 - y * W;
    float4 fx4 = *(const float4*)(flow + b*2*HW + n0);
    float4 fy4 = *(const float4*)(flow + b*2*HW + HW + n0);
    float4 d4  = *(const float4*)(depth + p0);
    int4   s4  = *(const int4*)(seg + p0);
    float fmn = fminf(fminf(fx4.x, fx4.y), fminf(fx4.z, fx4.w));
    float fmx = fmaxf(fmaxf(fx4.x, fx4.y), fmaxf(fx4.z, fx4.w));
    fmn = fminf(fmn, fminf(fminf(fy4.x, fy4.y), fminf(fy4.z, fy4.w)));
    fmx = fmaxf(fmx, fmaxf(fmaxf(fy4.x, fy4.y), fmaxf(fy4.z, fy4.w)));
    float smn = INFINITY, smx = -INFINITY;
    float fxa[4] = {fx4.x, fx4.y, fx4.z, fx4.w};
    float fya[4] = {fy4.x, fy4.y, fy4.z, fy4.w};
    float da[4]  = {d4.x, d4.y, d4.z, d4.w};
    int   sa[4]  = {s4.x, s4.y, s4.z, s4.w};
    int      t_j[4];
    unsigned r_j[4], e_j[4];
#pragma unroll
    for (int j = 0; j < 4; ++j) {
        float sx, sy;
        static_flow_P(iK, P, x0 + j, y, da[j], sx, sy);
        smn = fminf(smn, fminf(sx, sy));
        smx = fmaxf(smx, fmaxf(sx, sy));
        // target coords: round-half-even (rintf == jnp.round), clip
        int cxi = (int)rintf((float)(x0 + j) + fxa[j]);
        int cyi = (int)rintf((float)y + fya[j]);
        cxi = min(max(cxi, 0), W - 1);
        cyi = min(max(cyi, 0), H - 1);
        int t   = cyi / TR;                       // 0..31
        int pos = (cyi - t * TR) * W + cxi;       // < 3840 (12 bits)
        unsigned ns = ((unsigned)(n0 + j) << 1) | (sa[j] ? 1u : 0u); // 18 bits
        t_j[j] = t;
        e_j[j] = (ns << 12) | (unsigned)pos;      // 30 bits
        r_j[j] = atomicAdd(&ecnt[t], 1u);         // rank within block
    }
    __syncthreads();
    // counts out (winner-coalesced layout [b][t][blk]) + prefix
    if (threadIdx.x < TILES)
        cntA[(b * TILES + threadIdx.x) * BPB + blkInB] = ecnt[threadIdx.x];
    if (threadIdx.x == 0) {
        unsigned acc = 0;
#pragma unroll
        for (int t = 0; t < TILES; ++t) { ebase[t] = acc; acc += ecnt[t]; }
    }
    __syncthreads();
#pragma unroll
    for (int j = 0; j < 4; ++j)
        sbuf[ebase[t_j[j]] + r_j[j]] = e_j[j];
    __syncthreads();
    // coalesced write-out: consecutive i within a tile-run -> consecutive dst
    for (int i = threadIdx.x; i < EPB; i += TA) {
        int t = 0;
#pragma unroll
        for (int sh = 16; sh >= 1; sh >>= 1) {
            int nt = t + sh;
            if (nt < TILES && ebase[nt] <= (unsigned)i) t = nt;
        }
        size_t base = ((size_t)((b * TILES + t) * BPB + blkInB)) * SEGCAP;
        bkt[base + (i - ebase[t])] = sbuf[i];
    }

    blockRed4T<4>(fmn, fmx, smn, smx, sred, bc);
    if (threadIdx.x == 0) {
        redA[blockIdx.x*4+0] = fmn; redA[blockIdx.x*4+1] = fmx;
        redA[blockIdx.x*4+2] = smn; redA[blockIdx.x*4+3] = smx;
    }
}

// Dispatch 2, block-specialized:
//  blocks [0,GW): winner blocks (XCD-swizzled) — scan own bucket's 120
//    count-bounded segments (wave-per-segment), LDS atomicMax, in-LDS gather
//    (flow only; seg rides in the key), nontemporal-write bwd_flow + seg_ref.
//  blocks [GW,GW+GC): check blocks — re-reduce redA, compute check (exactly
//    one quad per thread), stash into out[0..BHW), partial min/max -> redB.
__global__ void __launch_bounds__(TPB)
kBW(const float* __restrict__ flow, const float* __restrict__ depth,
    const float* __restrict__ Km, const float* __restrict__ invK,
    const float* __restrict__ pose,
    const unsigned* __restrict__ cntA, const unsigned* __restrict__ bkt,
    const float* __restrict__ redA, float* __restrict__ redB,
    float* __restrict__ out)
{
    __shared__ unsigned smem[TRW];              // 15360 B
    if (blockIdx.x < GW) {
        // ---- winner block ----
        // XCD-aware mapping: xcd = bi&7 (round-robin model), 48 blocks/XCD.
        const int xcd = blockIdx.x & 7;
        const int k   = blockIdx.x >> 3;        // 0..47
        const int wp  = xcd * 48 + k;           // bijective [0,384)
        const int b   = wp >> 5;                // /TILES
        const int t   = wp & 31;                // %TILES

        for (int i = threadIdx.x; i < TRW; i += TPB) smem[i] = 0u;
        __syncthreads();

        const int wv = threadIdx.x >> 6, lane = threadIdx.x & 63;
        const unsigned* cbase = cntA + (b * TILES + t) * BPB;
        for (int s = wv; s < BPB; s += 16) {
            unsigned c = cbase[s];
            const unsigned* src =
                bkt + ((size_t)((b * TILES + t) * BPB + s)) * SEGCAP;
            for (unsigned i = lane; i < c; i += 64) {
                unsigned e = src[i];
                atomicMax(&smem[e & 4095u], (e >> 12) + 1u);
            }
        }
        __syncthreads();

        // in-LDS gather: tile targets n in [t*TRW, (t+1)*TRW)
        const float* fb = flow + b * 2 * HW;
        const int    nbase = t * TRW;
        for (int q = threadIdx.x; q < TRW/4; q += TPB) {
            uint4 w4 = *(const uint4*)(smem + q*4);
            unsigned wa[4] = {w4.x, w4.y, w4.z, w4.w};
            vfloat4 bx4, by4, sg4;
#pragma unroll
            for (int j = 0; j < 4; ++j) {
                float bx = 0.0f, by = 0.0f, sg = 0.0f;
                if (wa[j]) {
                    unsigned u = wa[j] - 1u;
                    int nw = (int)(u >> 1);
                    sg = (u & 1u) ? 1.0f : 0.0f;
                    bx = -fb[nw];
                    by = -fb[HW + nw];
                }
                bx4[j] = bx; by4[j] = by; sg4[j] = sg;
            }
            int n = nbase + q * 4;
            __builtin_nontemporal_store(bx4, (vfloat4*)(out + BHW + b*2*HW + n));
            __builtin_nontemporal_store(by4, (vfloat4*)(out + BHW + b*2*HW + HW + n));
            __builtin_nontemporal_store(sg4, (vfloat4*)(out + 3*BHW + b*HW + n));
        }
        return;
    }

    // ---- check block (exactly one quad per thread; GC*TPB*4 == BHW) ----
    float (*sred)[4] = (float(*)[4])smem;
    float* bc = (float*)(smem + 64);

    float gfmn = INFINITY, gfmx = -INFINITY, gsmn = INFINITY, gsmx = -INFINITY;
    for (int i = threadIdx.x; i < GA; i += TPB) {
        gfmn = fminf(gfmn, redA[i*4+0]); gfmx = fmaxf(gfmx, redA[i*4+1]);
        gsmn = fminf(gsmn, redA[i*4+2]); gsmx = fmaxf(gsmx, redA[i*4+3]);
    }
    blockRed4T<16>(gfmn, gfmx, gsmn, gsmx, sred, bc);

    float cmn = INFINITY, cmx = -INFINITY;
    const int cb = blockIdx.x - GW;
    {
        int g  = cb * TPB + threadIdx.x;       // < NQ by construction
        int p0 = g * 4;
        int b  = p0 / HW;
        float P[12];
        computeP(Km + b*16, pose + b*16, P);
        const float* iK = invK + b * 16;
        int n0 = p0 - b * HW;
        int y  = n0 / W;
        int x0 = n0 - y * W;
        float4 fx4 = *(const float4*)(flow + b*2*HW + n0);
        float4 fy4 = *(const float4*)(flow + b*2*HW + HW + n0);
        float4 d4  = *(const float4*)(depth + p0);
        float fxa[4] = {fx4.x, fx4.y, fx4.z, fx4.w};
        float fya[4] = {fy4.x, fy4.y, fy4.z, fy4.w};
        float da[4]  = {d4.x, d4.y, d4.z, d4.w};
        float4 cv;
        float* cva = (float*)&cv;
#pragma unroll
        for (int j = 0; j < 4; ++j) {
            float sx, sy;
            static_flow_P(iK, P, x0 + j, y, da[j], sx, sy);
            float dx = norm01(fxa[j], gfmn, gfmx) - norm01(sx, gsmn, gsmx);
            float dy = norm01(fya[j], gfmn, gfmx) - norm01(sy, gsmn, gsmx);
            float c = sqrtf(dx*dx + dy*dy);
            cva[j] = c;
            cmn = fminf(cmn, c); cmx = fmaxf(cmx, c);
        }
        *(float4*)(out + p0) = cv;   // stash check (re-read by kM: keep cached)
    }
    blockRed2T<16>(cmn, cmx, sred, bc);
    if (threadIdx.x == 0) { redB[cb*2] = cmn; redB[cb*2+1] = cmx; }
}

// Dispatch 3: re-reduce redB + threshold stashed check in-place -> motion_mask.
__global__ void __launch_bounds__(TA)
kM(const float* __restrict__ redB, float* __restrict__ out)
{
    __shared__ float sred[4][4];
    __shared__ float bc[4];

    float gcmn = INFINITY, gcmx = -INFINITY;
    for (int i = threadIdx.x; i < GC; i += TA) {
        gcmn = fminf(gcmn, redB[2*i]); gcmx = fmaxf(gcmx, redB[2*i+1]);
    }
    blockRed2T<4>(gcmn, gcmx, sred, bc);

    int p0 = (blockIdx.x * TA + threadIdx.x) * 4;   // < BHW by construction
    float4 c4 = *(const float4*)(out + p0);          // stashed check
    float ca[4] = {c4.x, c4.y, c4.z, c4.w};
    vfloat4 m4;
#pragma unroll
    for (int j = 0; j < 4; ++j) {
        float cn = (ca[j] - gcmn) / (gcmx - gcmn);
        m4[j] = (cn < 0.98f) ? 1.0f : 0.0f;
    }
    __builtin_nontemporal_store(m4, (vfloat4*)(out + p0));   // motion_mask
}

} // namespace

extern "C" void kernel_launch(void* const* d_in, const int* in_sizes, int n_in,
                              void* d_out, int out_size, void* d_ws, size_t ws_size,
                              hipStream_t stream) {
    const float* flow  = (const float*)d_in[0];
    const float* depth = (const float*)d_in[1];
    const float* Km    = (const float*)d_in[2];
    const float* invK  = (const float*)d_in[3];
    const float* pose  = (const float*)d_in[4];
    const int*   seg   = (const int*)d_in[5];
    float* out = (float*)d_out;

    float*    redA = (float*)d_ws;                               // GA*4 f32
    float*    redB = (float*)((char*)d_ws + 24576);              // GC*2 f32
    unsigned* cntA = (unsigned*)((char*)d_ws + 32768);           // B*TILES*BPB u32
    unsigned* bkt  = (unsigned*)((char*)d_ws + 262144);          // 188.7 MB

    kA <<<GA,    TA,  0, stream>>>(flow, depth, Km, invK, pose, seg,
                                   cntA, bkt, redA);
    kBW<<<CGRID, TPB, 0, stream>>>(flow, depth, Km, invK, pose,
                                   cntA, bkt, redA, redB, out);
    kM <<<GA,    TA,  0, stream>>>(redB, out);
}